// Round 2
// baseline (748.343 us; speedup 1.0000x reference)
//
#include <hip/hip_runtime.h>

// ---- filter / neuron constants (double, matching the Python reference) ----
#define EMD 0.8824969025845955      // exp(-1/8)
#define ESD 0.6065306597126334      // exp(-1/2)
#define A1C ((float)(EMD + ESD))                    // y[t-1] coeff
#define A2C ((float)(-(EMD * ESD)))                 // y[t-2] coeff
#define BC  ((float)((8.0 / 6.0) * (EMD - ESD)))    // x[t] coeff (ETA=8/6)
#define EMF ((float)EMD)                            // reset decay

// B=64, T=300. Layers: 300 -> 500 -> 200 -> 500 -> 300.
// IIR commutes with the GEMM (uniform per-feature coefficients, zero init),
// so GEMMs run on raw binary spikes and the IIR folds into the LIF pass.

// ---------------------------------------------------------------------------
// GEMM: C[b,o,t] = sum_i W[o,i] * X[b,i,t]
// X: [B,K,T] (T contiguous), W: [O,K], C: [B,O,T]
// 128(M=o) x 64(N=t) tile, 256 threads, 8x4 microtile, KC=16 LDS staging.
// k-accumulation strictly sequential -> bitwise-identical to round-1 currents.
// ---------------------------------------------------------------------------
#define KC 16
#define BM 128
#define BN 64

__global__ __launch_bounds__(256) void gemm_snn(
    const float* __restrict__ X, const float* __restrict__ W,
    float* __restrict__ C, int K, int O, int T)
{
    __shared__ float As[KC][BM + 4];   // row = 132 floats = 528 B (16B-aligned)
    __shared__ float Bs[KC][BN + 4];   // row = 68 floats = 272 B (16B-aligned)

    const int tx  = threadIdx.x;           // 0..15 -> N (t)
    const int ty  = threadIdx.y;           // 0..15 -> M (o)
    const int tid = ty * 16 + tx;
    const int t0  = blockIdx.x * BN;
    const int o0  = blockIdx.y * BM;
    const int b   = blockIdx.z;
    const float* Xb = X + (size_t)b * K * T;

    float acc[8][4] = {};

    const int nk = (K + KC - 1) / KC;
    for (int c = 0; c < nk; c++) {
        const int k0 = c * KC;
        // stage A (weights): As[kl][ol] = W[o0+ol][k0+kl]; 16-lane coalesced in k
        {
            const int kl   = tid & 15;
            const int orow = tid >> 4;
            const int k    = k0 + kl;
#pragma unroll
            for (int r = 0; r < 8; r++) {
                const int ol = orow + r * 16;
                const int o  = o0 + ol;
                As[kl][ol] = (o < O && k < K) ? W[(size_t)o * K + k] : 0.0f;
            }
        }
        // stage B (spikes): Bs[kl][tl] = X[b][k0+kl][t0+tl]; 64-lane coalesced in t
        {
            const int tl   = tid & 63;
            const int krow = tid >> 6;
            const int t    = t0 + tl;
#pragma unroll
            for (int r = 0; r < 4; r++) {
                const int kl = krow + r * 4;
                const int k  = k0 + kl;
                Bs[kl][tl] = (k < K && t < T) ? Xb[(size_t)k * T + t] : 0.0f;
            }
        }
        __syncthreads();
#pragma unroll
        for (int k = 0; k < KC; k++) {
            const float4 a0 = *reinterpret_cast<const float4*>(&As[k][ty * 8]);
            const float4 a1 = *reinterpret_cast<const float4*>(&As[k][ty * 8 + 4]);
            const float4 bv = *reinterpret_cast<const float4*>(&Bs[k][tx * 4]);
            const float a[8] = {a0.x, a0.y, a0.z, a0.w, a1.x, a1.y, a1.z, a1.w};
            const float bb[4] = {bv.x, bv.y, bv.z, bv.w};
#pragma unroll
            for (int i = 0; i < 8; i++) {
#pragma unroll
                for (int j = 0; j < 4; j++) acc[i][j] += a[i] * bb[j];
            }
        }
        __syncthreads();
    }

    float* Cb = C + (size_t)b * O * T;
    const bool full_t = (t0 + BN <= T);
#pragma unroll
    for (int i = 0; i < 8; i++) {
        const int o = o0 + ty * 8 + i;
        if (o < O) {
            float* Crow = Cb + (size_t)o * T + t0;
            if (full_t) {
                *reinterpret_cast<float4*>(Crow + tx * 4) =
                    make_float4(acc[i][0], acc[i][1], acc[i][2], acc[i][3]);
            } else {
#pragma unroll
                for (int j = 0; j < 4; j++) {
                    const int t = t0 + tx * 4 + j;
                    if (t < T) Crow[tx * 4 + j] = acc[i][j];
                }
            }
        }
    }
}

// ---------------------------------------------------------------------------
// Fused IIR + bias + LIF (in-place). One thread per (b,o) chain, sequential T.
// 8-deep float4 prefetch ring to cover HBM latency at ~2 waves/CU occupancy.
// ---------------------------------------------------------------------------
#define LIF_STEP(comp)                                                         \
    {                                                                          \
        float y = A1 * y1 + A2 * y2 + Bc * x.comp; y2 = y1; y1 = y;            \
        const float v = y + bi + r;                                            \
        const float s = (v >= 1.0f) ? 1.0f : 0.0f;                             \
        r = r * EMF - s; x.comp = s;                                           \
    }

__global__ __launch_bounds__(64) void lif_snn(
    float* __restrict__ C, const float* __restrict__ bias,
    const float* __restrict__ a1p, const float* __restrict__ a2p,
    const float* __restrict__ bp, int BO, int O, int T4)
{
    const int idx = blockIdx.x * 64 + threadIdx.x;
    if (idx >= BO) return;
    const float A1 = a1p[0], A2 = a2p[0], Bc = bp[0];
    const float bi = bias[idx % O];
    float4* row = reinterpret_cast<float4*>(C) + (size_t)idx * T4;

    float4 buf[8];
#pragma unroll
    for (int p = 0; p < 8; p++) buf[p] = row[p];   // T4 = 75 >= 8

    float y1 = 0.0f, y2 = 0.0f, r = 0.0f;
    for (int q = 0; q < T4; q++) {
        float4 x = buf[q & 7];
        if (q + 8 < T4) buf[q & 7] = row[q + 8];
        LIF_STEP(x) LIF_STEP(y) LIF_STEP(z) LIF_STEP(w)
        row[q] = x;
    }
}

// ---------------------------------------------------------------------------
// Layer-4 LIF fused with the fixed output dual-exp IIR filter.
// C: currents in / spikes out (first half of d_out); F: filt (second half).
// ---------------------------------------------------------------------------
__global__ __launch_bounds__(64) void lif4_snn(
    float* __restrict__ C, float* __restrict__ F,
    const float* __restrict__ bias,
    const float* __restrict__ a1p, const float* __restrict__ a2p,
    const float* __restrict__ bp, int BO, int O, int T4)
{
    const int idx = blockIdx.x * 64 + threadIdx.x;
    if (idx >= BO) return;
    const float A1 = a1p[0], A2 = a2p[0], Bc = bp[0];
    const float bi = bias[idx % O];
    float4* row  = reinterpret_cast<float4*>(C) + (size_t)idx * T4;
    float4* frow = reinterpret_cast<float4*>(F) + (size_t)idx * T4;

    float4 buf[8];
#pragma unroll
    for (int p = 0; p < 8; p++) buf[p] = row[p];

    float y1 = 0.0f, y2 = 0.0f, r = 0.0f;   // layer IIR + reset state
    float z1 = 0.0f, z2 = 0.0f;             // output-filter IIR state
    for (int q = 0; q < T4; q++) {
        float4 x = buf[q & 7];
        if (q + 8 < T4) buf[q & 7] = row[q + 8];
        float4 f;
        LIF_STEP(x) { float z = A1C * z1 + A2C * z2 + BC * x.x; z2 = z1; z1 = z; f.x = z; }
        LIF_STEP(y) { float z = A1C * z1 + A2C * z2 + BC * x.y; z2 = z1; z1 = z; f.y = z; }
        LIF_STEP(z) { float z = A1C * z1 + A2C * z2 + BC * x.z; z2 = z1; z1 = z; f.z = z; }
        LIF_STEP(w) { float z = A1C * z1 + A2C * z2 + BC * x.w; z2 = z1; z1 = z; f.w = z; }
        row[q]  = x;
        frow[q] = f;
    }
}

// ---------------------------------------------------------------------------
extern "C" void kernel_launch(void* const* d_in, const int* in_sizes, int n_in,
                              void* d_out, int out_size, void* d_ws, size_t ws_size,
                              hipStream_t stream)
{
    const float* inputs = (const float*)d_in[0];           // [64,300,300] binary
    const float* a1_1 = (const float*)d_in[1];
    const float* a2_1 = (const float*)d_in[2];
    const float* b_1  = (const float*)d_in[3];
    const float* W1   = (const float*)d_in[4];             // [500,300]
    const float* bias1= (const float*)d_in[5];
    const float* a1_2 = (const float*)d_in[6];
    const float* a2_2 = (const float*)d_in[7];
    const float* b_2  = (const float*)d_in[8];
    const float* W2   = (const float*)d_in[9];             // [200,500]
    const float* bias2= (const float*)d_in[10];
    const float* a1_3 = (const float*)d_in[11];
    const float* a2_3 = (const float*)d_in[12];
    const float* b_3  = (const float*)d_in[13];
    const float* W3   = (const float*)d_in[14];            // [500,200]
    const float* bias3= (const float*)d_in[15];
    const float* a1_4 = (const float*)d_in[16];
    const float* a2_4 = (const float*)d_in[17];
    const float* b_4  = (const float*)d_in[18];
    const float* W4   = (const float*)d_in[19];            // [300,500]
    const float* bias4= (const float*)d_in[20];

    const int B = 64, T = 300, T4 = T / 4;

    float* ws = (float*)d_ws;
    float* c1 = ws;                         // [64,500,300] (currents -> spikes, layers 1/3)
    float* c2 = ws + 9600000;               // [64,200,300]
    float* out = (float*)d_out;
    float* s4   = out;                      // [64,300,300]
    float* filt = out + 5760000;            // [64,300,300]

    const dim3 blk(16, 16);

    // Layer 1: 300 -> 500
    gemm_snn<<<dim3(5, 4, B), blk, 0, stream>>>(inputs, W1, c1, 300, 500, T);
    lif_snn<<<(B * 500 + 63) / 64, 64, 0, stream>>>(c1, bias1, a1_1, a2_1, b_1, B * 500, 500, T4);
    // Layer 2: 500 -> 200
    gemm_snn<<<dim3(5, 2, B), blk, 0, stream>>>(c1, W2, c2, 500, 200, T);
    lif_snn<<<(B * 200 + 63) / 64, 64, 0, stream>>>(c2, bias2, a1_2, a2_2, b_2, B * 200, 200, T4);
    // Layer 3: 200 -> 500 (reuse c1; s1 dead)
    gemm_snn<<<dim3(5, 4, B), blk, 0, stream>>>(c2, W3, c1, 200, 500, T);
    lif_snn<<<(B * 500 + 63) / 64, 64, 0, stream>>>(c1, bias3, a1_3, a2_3, b_3, B * 500, 500, T4);
    // Layer 4: 500 -> 300, currents into d_out; fused LIF + output filter
    gemm_snn<<<dim3(5, 3, B), blk, 0, stream>>>(c1, W4, s4, 500, 300, T);
    lif4_snn<<<(B * 300 + 63) / 64, 64, 0, stream>>>(s4, filt, bias4, a1_4, a2_4, b_4, B * 300, 300, T4);
}

// Round 3
// 662.722 us; speedup vs baseline: 1.1292x; 1.1292x over previous
//
#include <hip/hip_runtime.h>

// ---- filter / neuron constants (double, matching the Python reference) ----
#define EMD 0.8824969025845955      // exp(-1/8)
#define ESD 0.6065306597126334      // exp(-1/2)
#define A1C ((float)(EMD + ESD))                    // y[t-1] coeff
#define A2C ((float)(-(EMD * ESD)))                 // y[t-2] coeff
#define BC  ((float)((8.0 / 6.0) * (EMD - ESD)))    // x[t] coeff (ETA=8/6)
#define EMF ((float)EMD)                            // reset decay

// B=64, T=300. Layers: 300 -> 500 -> 200 -> 500 -> 300.
// IIR commutes with the GEMM (uniform per-feature coefficients, zero init),
// so GEMMs run on raw binary spikes and the IIR folds into the LIF pass.
// Accumulation is strictly sequential in k -> bitwise-matches the reference
// (absmax 0.0 in rounds 1-2); keep that property in every variant.

// ---------------------------------------------------------------------------
// GEMM: C[b,o,t] = sum_i W[o,i] * X[b,i,t]
// X: [B,K,T] (T contiguous), W: [O,K], C: [B,O,T]
// 64(o) x 64(t) tile, 128 threads (2 waves), 4o x 8t microtile, KC=32.
// Grid: (o-tiles, t-tiles, b) with o fastest so concurrent blocks share the
// X tile in L2 (round-2 FETCH showed 3.6x X over-fetch with t fastest).
// ---------------------------------------------------------------------------
#define KC 32
#define BM 64
#define BN 64

__global__ __launch_bounds__(128, 4) void gemm_snn(
    const float* __restrict__ X, const float* __restrict__ W,
    float* __restrict__ C, int K, int O, int T)
{
    __shared__ float As[KC][BM + 4];   // [k][o], row 272 B (16B-aligned)
    __shared__ float Bs[KC][BN + 4];   // [k][t]

    const int tid = threadIdx.x;       // 0..127
    const int tx  = tid & 7;           // t-octet index (8 t's each)
    const int ty  = tid >> 3;          // 0..15, o-quad index (4 o's each)
    const int o0  = blockIdx.x * BM;
    const int t0  = blockIdx.y * BN;
    const int b   = blockIdx.z;
    const float* Xb = X + (size_t)b * K * T;

    // staging decomposition
    const int akq = tid & 7;           // float4 index along k (0..7) for A
    const int aor = tid >> 3;          // o row (0..15), 4 passes -> 64 o
    const int btq = tid & 15;          // float4 index along t (0..15) for B
    const int bkr = tid >> 4;          // k row (0..7), 4 passes -> 32 k

    float acc[4][8] = {};

    const int nk = (K + KC - 1) / KC;
    for (int c = 0; c < nk; c++) {
        const int k0 = c * KC;
        // A: W[o0+ol][k0..k0+31]; lanes 0..7 read one 128 B o-row segment.
        // All our K's are multiples of 4, so float4 never straddles K.
#pragma unroll
        for (int r = 0; r < 4; r++) {
            const int ol = aor + r * 16;
            const int o  = o0 + ol;
            const int k  = k0 + akq * 4;
            float4 w = make_float4(0.f, 0.f, 0.f, 0.f);
            if (o < O && k + 3 < K)
                w = *reinterpret_cast<const float4*>(&W[(size_t)o * K + k]);
            As[akq * 4 + 0][ol] = w.x;
            As[akq * 4 + 1][ol] = w.y;
            As[akq * 4 + 2][ol] = w.z;
            As[akq * 4 + 3][ol] = w.w;
        }
        // B: X[b][k0+kl][t0..t0+63]; 256 B contiguous per 16 lanes. T=300 is a
        // multiple of 4 and t0 is, so float4 never straddles T.
#pragma unroll
        for (int r = 0; r < 4; r++) {
            const int kl = bkr + r * 8;
            const int k  = k0 + kl;
            const int t  = t0 + btq * 4;
            float4 x = make_float4(0.f, 0.f, 0.f, 0.f);
            if (k < K && t + 3 < T)
                x = *reinterpret_cast<const float4*>(&Xb[(size_t)k * T + t]);
            *reinterpret_cast<float4*>(&Bs[kl][btq * 4]) = x;
        }
        __syncthreads();
#pragma unroll
        for (int k = 0; k < KC; k++) {
            const float4 av = *reinterpret_cast<const float4*>(&As[k][ty * 4]);
            const float4 x0 = *reinterpret_cast<const float4*>(&Bs[k][tx * 8]);
            const float4 x1 = *reinterpret_cast<const float4*>(&Bs[k][tx * 8 + 4]);
            const float a[4]  = {av.x, av.y, av.z, av.w};
            const float xv[8] = {x0.x, x0.y, x0.z, x0.w, x1.x, x1.y, x1.z, x1.w};
#pragma unroll
            for (int i = 0; i < 4; i++) {
#pragma unroll
                for (int j = 0; j < 8; j++) acc[i][j] += a[i] * xv[j];
            }
        }
        __syncthreads();
    }

    float* Cb = C + (size_t)b * O * T;
#pragma unroll
    for (int i = 0; i < 4; i++) {
        const int o = o0 + ty * 4 + i;
        if (o < O) {
            float* Crow = Cb + (size_t)o * T + t0 + tx * 8;
            const int t = t0 + tx * 8;
            if (t + 3 < T)
                *reinterpret_cast<float4*>(Crow) =
                    make_float4(acc[i][0], acc[i][1], acc[i][2], acc[i][3]);
            if (t + 7 < T)
                *reinterpret_cast<float4*>(Crow + 4) =
                    make_float4(acc[i][4], acc[i][5], acc[i][6], acc[i][7]);
        }
    }
}

// ---------------------------------------------------------------------------
// Fused IIR + bias + LIF (in-place). One thread per (b,o) chain, sequential T.
// 8-deep float4 prefetch ring to cover HBM latency at low occupancy.
// ---------------------------------------------------------------------------
#define LIF_STEP(comp)                                                         \
    {                                                                          \
        float y = A1 * y1 + A2 * y2 + Bc * x.comp; y2 = y1; y1 = y;            \
        const float v = y + bi + r;                                            \
        const float s = (v >= 1.0f) ? 1.0f : 0.0f;                             \
        r = r * EMF - s; x.comp = s;                                           \
    }

__global__ __launch_bounds__(64) void lif_snn(
    float* __restrict__ C, const float* __restrict__ bias,
    const float* __restrict__ a1p, const float* __restrict__ a2p,
    const float* __restrict__ bp, int BO, int O, int T4)
{
    const int idx = blockIdx.x * 64 + threadIdx.x;
    if (idx >= BO) return;
    const float A1 = a1p[0], A2 = a2p[0], Bc = bp[0];
    const float bi = bias[idx % O];
    float4* row = reinterpret_cast<float4*>(C) + (size_t)idx * T4;

    float4 buf[8];
#pragma unroll
    for (int p = 0; p < 8; p++) buf[p] = row[p];   // T4 = 75 >= 8

    float y1 = 0.0f, y2 = 0.0f, r = 0.0f;
    for (int q = 0; q < T4; q++) {
        float4 x = buf[q & 7];
        if (q + 8 < T4) buf[q & 7] = row[q + 8];
        LIF_STEP(x) LIF_STEP(y) LIF_STEP(z) LIF_STEP(w)
        row[q] = x;
    }
}

// ---------------------------------------------------------------------------
// Layer-4 LIF fused with the fixed output dual-exp IIR filter.
// C: currents in / spikes out (first half of d_out); F: filt (second half).
// ---------------------------------------------------------------------------
__global__ __launch_bounds__(64) void lif4_snn(
    float* __restrict__ C, float* __restrict__ F,
    const float* __restrict__ bias,
    const float* __restrict__ a1p, const float* __restrict__ a2p,
    const float* __restrict__ bp, int BO, int O, int T4)
{
    const int idx = blockIdx.x * 64 + threadIdx.x;
    if (idx >= BO) return;
    const float A1 = a1p[0], A2 = a2p[0], Bc = bp[0];
    const float bi = bias[idx % O];
    float4* row  = reinterpret_cast<float4*>(C) + (size_t)idx * T4;
    float4* frow = reinterpret_cast<float4*>(F) + (size_t)idx * T4;

    float4 buf[8];
#pragma unroll
    for (int p = 0; p < 8; p++) buf[p] = row[p];

    float y1 = 0.0f, y2 = 0.0f, r = 0.0f;   // layer IIR + reset state
    float z1 = 0.0f, z2 = 0.0f;             // output-filter IIR state
    for (int q = 0; q < T4; q++) {
        float4 x = buf[q & 7];
        if (q + 8 < T4) buf[q & 7] = row[q + 8];
        float4 f;
        LIF_STEP(x) { float z = A1C * z1 + A2C * z2 + BC * x.x; z2 = z1; z1 = z; f.x = z; }
        LIF_STEP(y) { float z = A1C * z1 + A2C * z2 + BC * x.y; z2 = z1; z1 = z; f.y = z; }
        LIF_STEP(z) { float z = A1C * z1 + A2C * z2 + BC * x.z; z2 = z1; z1 = z; f.z = z; }
        LIF_STEP(w) { float z = A1C * z1 + A2C * z2 + BC * x.w; z2 = z1; z1 = z; f.w = z; }
        row[q]  = x;
        frow[q] = f;
    }
}

// ---------------------------------------------------------------------------
extern "C" void kernel_launch(void* const* d_in, const int* in_sizes, int n_in,
                              void* d_out, int out_size, void* d_ws, size_t ws_size,
                              hipStream_t stream)
{
    const float* inputs = (const float*)d_in[0];           // [64,300,300] binary
    const float* a1_1 = (const float*)d_in[1];
    const float* a2_1 = (const float*)d_in[2];
    const float* b_1  = (const float*)d_in[3];
    const float* W1   = (const float*)d_in[4];             // [500,300]
    const float* bias1= (const float*)d_in[5];
    const float* a1_2 = (const float*)d_in[6];
    const float* a2_2 = (const float*)d_in[7];
    const float* b_2  = (const float*)d_in[8];
    const float* W2   = (const float*)d_in[9];             // [200,500]
    const float* bias2= (const float*)d_in[10];
    const float* a1_3 = (const float*)d_in[11];
    const float* a2_3 = (const float*)d_in[12];
    const float* b_3  = (const float*)d_in[13];
    const float* W3   = (const float*)d_in[14];            // [500,200]
    const float* bias3= (const float*)d_in[15];
    const float* a1_4 = (const float*)d_in[16];
    const float* a2_4 = (const float*)d_in[17];
    const float* b_4  = (const float*)d_in[18];
    const float* W4   = (const float*)d_in[19];            // [300,500]
    const float* bias4= (const float*)d_in[20];

    const int B = 64, T = 300, T4 = T / 4;

    float* ws = (float*)d_ws;
    float* c1 = ws;                         // [64,500,300] (currents -> spikes, layers 1/3)
    float* c2 = ws + 9600000;               // [64,200,300]
    float* out = (float*)d_out;
    float* s4   = out;                      // [64,300,300]
    float* filt = out + 5760000;            // [64,300,300]

    // Grid: x = o-tiles (fastest -> L2 shares the X tile), y = t-tiles, z = b
    // Layer 1: 300 -> 500
    gemm_snn<<<dim3(8, 5, B), 128, 0, stream>>>(inputs, W1, c1, 300, 500, T);
    lif_snn<<<(B * 500 + 63) / 64, 64, 0, stream>>>(c1, bias1, a1_1, a2_1, b_1, B * 500, 500, T4);
    // Layer 2: 500 -> 200
    gemm_snn<<<dim3(4, 5, B), 128, 0, stream>>>(c1, W2, c2, 500, 200, T);
    lif_snn<<<(B * 200 + 63) / 64, 64, 0, stream>>>(c2, bias2, a1_2, a2_2, b_2, B * 200, 200, T4);
    // Layer 3: 200 -> 500 (reuse c1; s1 dead)
    gemm_snn<<<dim3(8, 5, B), 128, 0, stream>>>(c2, W3, c1, 200, 500, T);
    lif_snn<<<(B * 500 + 63) / 64, 64, 0, stream>>>(c1, bias3, a1_3, a2_3, b_3, B * 500, 500, T4);
    // Layer 4: 500 -> 300, currents into d_out; fused LIF + output filter
    gemm_snn<<<dim3(5, 5, B), 128, 0, stream>>>(c1, W4, s4, 500, 300, T);
    lif4_snn<<<(B * 300 + 63) / 64, 64, 0, stream>>>(s4, filt, bias4, a1_4, a2_4, b_4, B * 300, 300, T4);
}